// Round 17
// baseline (126.602 us; speedup 1.0000x reference)
//
#include <hip/hip_runtime.h>

#define NV    10
#define DD    2048
#define TAPS  25
#define CHUNK 128             // channels per staging chunk
#define NCHH  8               // chunks per HALF (1024 channels)
#define NGRP  (DD / 64)       // 32 groups of 64 channels
#define HGRP  16              // groups per half
#define OB    32              // o's per out-block (33-stride LDS -> 4 blocks/CU)

typedef __attribute__((address_space(1))) const unsigned int gu32;
typedef __attribute__((address_space(3))) unsigned int lu32;

__device__ __forceinline__ float bsign(float v) {
    return (v > 0.0f) ? 1.0f : ((v < 0.0f) ? -1.0f : 0.0f);
}

// G2[half][tap][n][o] = sum over this half's 1024 channels (exact int in f32).
// R17 = R16's g byte-identical EXCEPT the value masks are built in-register in
// the prologue (threads 0..159, 16 INDEPENDENT float4 loads + local bit-build;
// no serial ballot chain = not R12's poison), killing the vpack dispatch.
__global__ __launch_bounds__(256) void g_kernel(
        const float* __restrict__ values,
        const float* __restrict__ w,
        float* __restrict__ G) {
    const int bid  = blockIdx.x;
    const int o    = bid >> 1;
    const int half = bid & 1;
    const int t    = threadIdx.x;
    const int lane = t & 63;
    const int wv   = t >> 6;

    __shared__ float ls_raw[CHUNK * TAPS + 32];          // 3200 floats, linear
    __shared__ unsigned long long s_wnz[2][TAPS * 2];    // double-buffered chunk masks
    __shared__ unsigned long long s_wng[2][TAPS * 2];
    __shared__ unsigned long long s_vnz[NV * HGRP];      // this half's value masks [n][gl]
    __shared__ unsigned long long s_vng[NV * HGRP];

    const float* wo = w + (size_t)o * (DD * TAPS) + (size_t)half * (1024 * TAPS);

    // pack chunk in ls_raw -> mask buffer bi: 14 tasks = 7 tap-quads x 2 subgroups.
    // Static unroll 4/wave; quad overread at tap 24 is in-bounds (pad) and discarded.
    #define PACK_CHUNK(bi)                                                        \
    {                                                                             \
        _Pragma("unroll")                                                         \
        for (int i = 0; i < 4; ++i) {                                             \
            const int tk = wv + 4 * i;                                            \
            if (tk < 14) {                                                        \
                const int q  = tk >> 1;                                           \
                const int sb = tk & 1;                                            \
                const int t0 = 4 * q;                                             \
                const int ba = (sb * 64 + lane) * TAPS + t0;                      \
                float a0 = ls_raw[ba + 0];                                        \
                float a1 = ls_raw[ba + 1];                                        \
                float a2 = ls_raw[ba + 2];                                        \
                float a3 = ls_raw[ba + 3];                                        \
                unsigned long long z0 = __ballot(a0 != 0.0f);                     \
                unsigned long long g0 = __ballot(a0 <  0.0f);                     \
                unsigned long long z1 = __ballot(a1 != 0.0f);                     \
                unsigned long long g1 = __ballot(a1 <  0.0f);                     \
                unsigned long long z2 = __ballot(a2 != 0.0f);                     \
                unsigned long long g2 = __ballot(a2 <  0.0f);                     \
                unsigned long long z3 = __ballot(a3 != 0.0f);                     \
                unsigned long long g3 = __ballot(a3 <  0.0f);                     \
                if (lane == 0) {                                                  \
                    s_wnz[bi][(t0 + 0) * 2 + sb] = z0;                            \
                    s_wng[bi][(t0 + 0) * 2 + sb] = g0;                            \
                    if (t0 + 1 < TAPS) {                                          \
                        s_wnz[bi][(t0 + 1) * 2 + sb] = z1;                        \
                        s_wng[bi][(t0 + 1) * 2 + sb] = g1;                        \
                        s_wnz[bi][(t0 + 2) * 2 + sb] = z2;                        \
                        s_wng[bi][(t0 + 2) * 2 + sb] = g2;                        \
                        s_wnz[bi][(t0 + 3) * 2 + sb] = z3;                        \
                        s_wng[bi][(t0 + 3) * 2 + sb] = g3;                        \
                    }                                                             \
                }                                                                 \
            }                                                                     \
        }                                                                         \
    }

    // ---- prologue: chunk 0 into flight, then in-register mask build (hidden) ----
    for (int e = t; e < (CHUNK * TAPS) / 4; e += 256) {
        __builtin_amdgcn_global_load_lds((gu32*)(wo + 4 * e),
                                         (lu32*)(ls_raw + 4 * (e - lane)), 16, 0, 0);
    }
    if (t < NV * HGRP) {                 // 160 threads: one (n, group) each
        const int n  = t / HGRP;
        const int gl = t - n * HGRP;
        const float4* vp = (const float4*)(values + n * DD + half * 1024 + gl * 64);
        unsigned long long nz = 0ull, ng = 0ull;
        #pragma unroll
        for (int j = 0; j < 16; ++j) {   // 16 INDEPENDENT loads (ILP), local bit ops
            const float4 v = vp[j];
            if (v.x != 0.0f) nz |= 1ull << (4 * j + 0);
            if (v.x <  0.0f) ng |= 1ull << (4 * j + 0);
            if (v.y != 0.0f) nz |= 1ull << (4 * j + 1);
            if (v.y <  0.0f) ng |= 1ull << (4 * j + 1);
            if (v.z != 0.0f) nz |= 1ull << (4 * j + 2);
            if (v.z <  0.0f) ng |= 1ull << (4 * j + 2);
            if (v.w != 0.0f) nz |= 1ull << (4 * j + 3);
            if (v.w <  0.0f) ng |= 1ull << (4 * j + 3);
        }
        s_vnz[n * HGRP + gl] = nz;       // bit i = channel half*1024 + gl*64 + i
        s_vng[n * HGRP + gl] = ng;
    }
    __syncthreads();          // drains vmcnt: chunk 0 staged; value masks visible
    PACK_CHUNK(0)
    __syncthreads();          // pack(0) visible; ls_raw free for chunk 1

    const int tap = t / NV;   // accum ownership: t<250 -> (tap, n)
    const int n   = t - tap * NV;
    int acc = 0;

    // ---- main loop: per iter = stage(ch) || accumulate(ch-1), drain, pack(ch) ----
    for (int ch = 1; ch <= NCHH; ++ch) {
        if (ch < NCHH) {
            const float* src = wo + (size_t)(ch * CHUNK) * TAPS;
            for (int e = t; e < (CHUNK * TAPS) / 4; e += 256) {
                __builtin_amdgcn_global_load_lds((gu32*)(src + 4 * e),
                                                 (lu32*)(ls_raw + 4 * (e - lane)), 16, 0, 0);
            }
        }
        // accumulate chunk ch-1 in the staging-latency shadow (reads masks only)
        if (t < NV * TAPS) {
            const int pb = (ch - 1) & 1;
            #pragma unroll
            for (int sub = 0; sub < 2; ++sub) {
                unsigned long long wnz = s_wnz[pb][tap * 2 + sub];
                unsigned long long wng = s_wng[pb][tap * 2 + sub];
                unsigned long long vz  = s_vnz[n * HGRP + (ch - 1) * 2 + sub];
                unsigned long long vg  = s_vng[n * HGRP + (ch - 1) * 2 + sub];
                unsigned long long nzb = wnz & vz;
                // exact: S += popc(bothnz) - 2*popc(signdiff & bothnz); zeros handled
                acc += (int)__popcll(nzb) - 2 * (int)__popcll((wng ^ vg) & nzb);
            }
        }
        if (ch < NCHH) {
            __syncthreads();      // vmcnt drain: ls_raw = chunk ch
            PACK_CHUNK(ch & 1)
            __syncthreads();      // pack(ch) visible before acc(ch) / stage(ch+1)
        }
    }
    #undef PACK_CHUNK

    if (t < NV * TAPS) {
        // G2[half][tap*10+n][o]; each half-sum is an exact integer, |.| <= 25600
        G[((size_t)(half * (TAPS * NV) + tap * NV + n) << 11) + o] = (float)acc;
    }
}

// ---- out_kernel: R16 gather with 32-o strips (s_G 33 KB -> 4 blocks/CU,
// grid 1024). Halves summed at stage (exact ints); bias once -> bit-exact. ----
__global__ __launch_bounds__(256) void out_kernel(
        const float* __restrict__ x,
        const float* __restrict__ G,
        const float* __restrict__ bias,
        float* __restrict__ out) {
    const int b     = blockIdx.x >> 6;     // 16 batches
    const int oc    = blockIdx.x & 63;     // 64 o-strips of 32
    const int obase = oc * OB;
    const int t     = threadIdx.x;
    const int lane  = t & 63;
    const int oq    = t >> 6;              // 0..3: o residue class per wave

    __shared__ float s_G[TAPS * NV * 33];  // [tap*10+n][33]: +1 pad -> nn spreads banks
    __shared__ int   s_idx[28 * 28];
    __shared__ float s_bias[OB];

    // stage G strip: 250 rows x 32 floats (8 float4); sum the two K-halves (exact ints)
    for (int e = t; e < TAPS * NV * 8; e += 256) {
        const int r  = e >> 3;
        const int li = (e & 7) << 2;
        const float4 va = *(const float4*)(G + ((size_t)r << 11) + obase + li);
        const float4 vb = *(const float4*)(G + ((size_t)(r + TAPS * NV) << 11) + obase + li);
        s_G[r * 33 + li]     = va.x + vb.x;
        s_G[r * 33 + li + 1] = va.y + vb.y;
        s_G[r * 33 + li + 2] = va.z + vb.z;
        s_G[r * 33 + li + 3] = va.w + vb.w;
    }
    for (int e = t; e < 28 * 28; e += 256) {
        s_idx[e] = (int)(x[b * 784 + e] * 9.0f);   // trunc, matches .astype(int32)
    }
    if (t < OB) s_bias[t] = bias[obase + t];
    __syncthreads();

    for (int grp = 0; grp < 3; ++grp) {
        const int pos = grp * 64 + lane;
        if (pos < 144) {
            const int oh = pos / 12;
            const int ow = pos - oh * 12;
            int rr[25];                              // static-indexed (fully unrolled)
            #pragma unroll
            for (int kh = 0; kh < 5; ++kh) {
                const int row = (oh * 2 + kh) * 28 + ow * 2;
                #pragma unroll
                for (int kw = 0; kw < 5; ++kw) {
                    const int nn = s_idx[row + kw];          // per-lane index
                    rr[kh * 5 + kw] = (kh * 5 + kw) * 330 + nn * 33;
                }
            }
            for (int ol = oq; ol < OB; ol += 4) {    // 8 o's reuse the 25 offsets
                float acc = 0.0f;                    // integer-exact accumulation
                #pragma unroll
                for (int tp = 0; tp < TAPS; ++tp) {
                    acc += s_G[rr[tp] + ol];         // 10 banks + broadcast: conflict-free
                }
                // bias added once after exact int sum -> bit-exact sign
                out[((size_t)(b * DD + obase + ol)) * 144 + pos] = bsign(acc + s_bias[ol]);
            }
        }
    }
}

extern "C" void kernel_launch(void* const* d_in, const int* in_sizes, int n_in,
                              void* d_out, int out_size, void* d_ws, size_t ws_size,
                              hipStream_t stream) {
    const float* x      = (const float*)d_in[0];   // [16,1,28,28]
    const float* values = (const float*)d_in[1];   // [10,2048]
    const float* w      = (const float*)d_in[2];   // [2048,2048,5,5] OIHW
    const float* bias   = (const float*)d_in[3];   // [2048]
    float* out = (float*)d_out;                    // [16,2048,12,12]
    float* G   = (float*)d_ws;                     // 2 x 2 MB half-G arrays

    hipLaunchKernelGGL(g_kernel, dim3(2 * DD), dim3(256), 0, stream, values, w, G);
    hipLaunchKernelGGL(out_kernel, dim3(16 * (DD / OB)), dim3(256), 0, stream, x, G, bias, out);
}

// Round 18
// 117.446 us; speedup vs baseline: 1.0780x; 1.0780x over previous
//
#include <hip/hip_runtime.h>

#define NV    10
#define DD    2048
#define TAPS  25
#define CHUNK 128             // channels per staging chunk
#define NCHH  8               // chunks per HALF (1024 channels)
#define NGRP  (DD / 64)       // 32 groups of 64 channels
#define HGRP  16              // groups per half
#define OB    32              // o's per out-block (33-stride LDS -> 4 blocks/CU)

typedef __attribute__((address_space(1))) const unsigned int gu32;
typedef __attribute__((address_space(3))) unsigned int lu32;

__device__ __forceinline__ float bsign(float v) {
    return (v > 0.0f) ? 1.0f : ((v < 0.0f) ? -1.0f : 0.0f);
}

// Pack sign/nonzero bitmasks of values: one block per (n, 64-ch group).
// SEPARATE kernel — every in-g fusion attempt regressed (R12 +27us, R17 +9us).
__global__ __launch_bounds__(64) void vpack_kernel(
        const float* __restrict__ values,
        unsigned long long* __restrict__ vnz,
        unsigned long long* __restrict__ vng) {
    const int b    = blockIdx.x;      // 0..319
    const int n    = b >> 5;
    const int g    = b & 31;
    const int lane = threadIdx.x;
    float f = values[n * DD + g * 64 + lane];
    unsigned long long nz = __ballot(f != 0.0f);
    unsigned long long ng = __ballot(f < 0.0f);
    if (lane == 0) {
        vnz[n * NGRP + g] = nz;
        vng[n * NGRP + g] = ng;
    }
}

// G2[half][tap][n][o] = sum over this half's 1024 channels (exact int in f32).
// VERBATIM R16 g (the 117.2 best): half-K cohort stagger, pack-quads,
// 2 barriers/chunk, masks preloaded from global, 8 blocks/CU.
__global__ __launch_bounds__(256) void g_kernel(
        const float* __restrict__ w,
        const unsigned long long* __restrict__ gvnz,
        const unsigned long long* __restrict__ gvng,
        float* __restrict__ G) {
    const int bid  = blockIdx.x;
    const int o    = bid >> 1;
    const int half = bid & 1;
    const int t    = threadIdx.x;
    const int lane = t & 63;
    const int wv   = t >> 6;

    __shared__ float ls_raw[CHUNK * TAPS + 32];          // 3200 floats, linear
    __shared__ unsigned long long s_wnz[2][TAPS * 2];    // double-buffered chunk masks
    __shared__ unsigned long long s_wng[2][TAPS * 2];
    __shared__ unsigned long long s_vnz[NV * HGRP];      // this half's value masks [n][gl]
    __shared__ unsigned long long s_vng[NV * HGRP];

    const float* wo = w + (size_t)o * (DD * TAPS) + (size_t)half * (1024 * TAPS);

    // pack chunk in ls_raw -> mask buffer bi: 14 tasks = 7 tap-quads x 2 subgroups.
    // Static unroll 4/wave; quad overread at tap 24 is in-bounds (pad) and discarded.
    #define PACK_CHUNK(bi)                                                        \
    {                                                                             \
        _Pragma("unroll")                                                         \
        for (int i = 0; i < 4; ++i) {                                             \
            const int tk = wv + 4 * i;                                            \
            if (tk < 14) {                                                        \
                const int q  = tk >> 1;                                           \
                const int sb = tk & 1;                                            \
                const int t0 = 4 * q;                                             \
                const int ba = (sb * 64 + lane) * TAPS + t0;                      \
                float a0 = ls_raw[ba + 0];                                        \
                float a1 = ls_raw[ba + 1];                                        \
                float a2 = ls_raw[ba + 2];                                        \
                float a3 = ls_raw[ba + 3];                                        \
                unsigned long long z0 = __ballot(a0 != 0.0f);                     \
                unsigned long long g0 = __ballot(a0 <  0.0f);                     \
                unsigned long long z1 = __ballot(a1 != 0.0f);                     \
                unsigned long long g1 = __ballot(a1 <  0.0f);                     \
                unsigned long long z2 = __ballot(a2 != 0.0f);                     \
                unsigned long long g2 = __ballot(a2 <  0.0f);                     \
                unsigned long long z3 = __ballot(a3 != 0.0f);                     \
                unsigned long long g3 = __ballot(a3 <  0.0f);                     \
                if (lane == 0) {                                                  \
                    s_wnz[bi][(t0 + 0) * 2 + sb] = z0;                            \
                    s_wng[bi][(t0 + 0) * 2 + sb] = g0;                            \
                    if (t0 + 1 < TAPS) {                                          \
                        s_wnz[bi][(t0 + 1) * 2 + sb] = z1;                        \
                        s_wng[bi][(t0 + 1) * 2 + sb] = g1;                        \
                        s_wnz[bi][(t0 + 2) * 2 + sb] = z2;                        \
                        s_wng[bi][(t0 + 2) * 2 + sb] = g2;                        \
                        s_wnz[bi][(t0 + 3) * 2 + sb] = z3;                        \
                        s_wng[bi][(t0 + 3) * 2 + sb] = g3;                        \
                    }                                                             \
                }                                                                 \
            }                                                                     \
        }                                                                         \
    }

    // ---- prologue: chunk 0 into flight, then this half's mask preload (2.5 KB) ----
    for (int e = t; e < (CHUNK * TAPS) / 4; e += 256) {
        __builtin_amdgcn_global_load_lds((gu32*)(wo + 4 * e),
                                         (lu32*)(ls_raw + 4 * (e - lane)), 16, 0, 0);
    }
    if (t < NV * HGRP) {                                 // 160 threads, L2-hot
        const int n  = t >> 4;
        const int gl = t & 15;
        s_vnz[t] = gvnz[n * NGRP + half * HGRP + gl];
        s_vng[t] = gvng[n * NGRP + half * HGRP + gl];
    }
    __syncthreads();          // drains vmcnt: chunk 0 staged; value masks visible
    PACK_CHUNK(0)
    __syncthreads();          // pack(0) visible; ls_raw free for chunk 1

    const int tap = t / NV;   // accum ownership: t<250 -> (tap, n)
    const int n   = t - tap * NV;
    int acc = 0;

    // ---- main loop: per iter = stage(ch) || accumulate(ch-1), drain, pack(ch) ----
    for (int ch = 1; ch <= NCHH; ++ch) {
        if (ch < NCHH) {
            const float* src = wo + (size_t)(ch * CHUNK) * TAPS;
            for (int e = t; e < (CHUNK * TAPS) / 4; e += 256) {
                __builtin_amdgcn_global_load_lds((gu32*)(src + 4 * e),
                                                 (lu32*)(ls_raw + 4 * (e - lane)), 16, 0, 0);
            }
        }
        // accumulate chunk ch-1 in the staging-latency shadow (reads masks only)
        if (t < NV * TAPS) {
            const int pb = (ch - 1) & 1;
            #pragma unroll
            for (int sub = 0; sub < 2; ++sub) {
                unsigned long long wnz = s_wnz[pb][tap * 2 + sub];
                unsigned long long wng = s_wng[pb][tap * 2 + sub];
                unsigned long long vz  = s_vnz[n * HGRP + (ch - 1) * 2 + sub];
                unsigned long long vg  = s_vng[n * HGRP + (ch - 1) * 2 + sub];
                unsigned long long nzb = wnz & vz;
                // exact: S += popc(bothnz) - 2*popc(signdiff & bothnz); zeros handled
                acc += (int)__popcll(nzb) - 2 * (int)__popcll((wng ^ vg) & nzb);
            }
        }
        if (ch < NCHH) {
            __syncthreads();      // vmcnt drain: ls_raw = chunk ch
            PACK_CHUNK(ch & 1)
            __syncthreads();      // pack(ch) visible before acc(ch) / stage(ch+1)
        }
    }
    #undef PACK_CHUNK

    if (t < NV * TAPS) {
        // G2[half][tap*10+n][o]; each half-sum is an exact integer, |.| <= 25600
        G[((size_t)(half * (TAPS * NV) + tap * NV + n) << 11) + o] = (float)acc;
    }
}

// ---- out_kernel: R17's 32-o-strip version (s_G 33 KB -> 4 blocks/CU, grid 1024).
// Halves summed at stage (exact ints); bias added once -> bit-exact sign. ----
__global__ __launch_bounds__(256) void out_kernel(
        const float* __restrict__ x,
        const float* __restrict__ G,
        const float* __restrict__ bias,
        float* __restrict__ out) {
    const int b     = blockIdx.x >> 6;     // 16 batches
    const int oc    = blockIdx.x & 63;     // 64 o-strips of 32
    const int obase = oc * OB;
    const int t     = threadIdx.x;
    const int lane  = t & 63;
    const int oq    = t >> 6;              // 0..3: o residue class per wave

    __shared__ float s_G[TAPS * NV * 33];  // [tap*10+n][33]: +1 pad -> nn spreads banks
    __shared__ int   s_idx[28 * 28];
    __shared__ float s_bias[OB];

    // stage G strip: 250 rows x 32 floats (8 float4); sum the two K-halves (exact ints)
    for (int e = t; e < TAPS * NV * 8; e += 256) {
        const int r  = e >> 3;
        const int li = (e & 7) << 2;
        const float4 va = *(const float4*)(G + ((size_t)r << 11) + obase + li);
        const float4 vb = *(const float4*)(G + ((size_t)(r + TAPS * NV) << 11) + obase + li);
        s_G[r * 33 + li]     = va.x + vb.x;
        s_G[r * 33 + li + 1] = va.y + vb.y;
        s_G[r * 33 + li + 2] = va.z + vb.z;
        s_G[r * 33 + li + 3] = va.w + vb.w;
    }
    for (int e = t; e < 28 * 28; e += 256) {
        s_idx[e] = (int)(x[b * 784 + e] * 9.0f);   // trunc, matches .astype(int32)
    }
    if (t < OB) s_bias[t] = bias[obase + t];
    __syncthreads();

    for (int grp = 0; grp < 3; ++grp) {
        const int pos = grp * 64 + lane;
        if (pos < 144) {
            const int oh = pos / 12;
            const int ow = pos - oh * 12;
            int rr[25];                              // static-indexed (fully unrolled)
            #pragma unroll
            for (int kh = 0; kh < 5; ++kh) {
                const int row = (oh * 2 + kh) * 28 + ow * 2;
                #pragma unroll
                for (int kw = 0; kw < 5; ++kw) {
                    const int nn = s_idx[row + kw];          // per-lane index
                    rr[kh * 5 + kw] = (kh * 5 + kw) * 330 + nn * 33;
                }
            }
            for (int ol = oq; ol < OB; ol += 4) {    // 8 o's reuse the 25 offsets
                float acc = 0.0f;                    // integer-exact accumulation
                #pragma unroll
                for (int tp = 0; tp < TAPS; ++tp) {
                    acc += s_G[rr[tp] + ol];         // 10 banks + broadcast: conflict-free
                }
                // bias added once after exact int sum -> bit-exact sign
                out[((size_t)(b * DD + obase + ol)) * 144 + pos] = bsign(acc + s_bias[ol]);
            }
        }
    }
}

extern "C" void kernel_launch(void* const* d_in, const int* in_sizes, int n_in,
                              void* d_out, int out_size, void* d_ws, size_t ws_size,
                              hipStream_t stream) {
    const float* x      = (const float*)d_in[0];   // [16,1,28,28]
    const float* values = (const float*)d_in[1];   // [10,2048]
    const float* w      = (const float*)d_in[2];   // [2048,2048,5,5] OIHW
    const float* bias   = (const float*)d_in[3];   // [2048]
    float* out = (float*)d_out;                    // [16,2048,12,12]

    unsigned long long* vnz = (unsigned long long*)d_ws;          // 2560 B
    unsigned long long* vng = vnz + NV * NGRP;                    // 2560 B
    float* G = (float*)((char*)d_ws + 8192);                      // 2 x 2 MB halves

    hipLaunchKernelGGL(vpack_kernel, dim3(NV * NGRP), dim3(64), 0, stream, values, vnz, vng);
    hipLaunchKernelGGL(g_kernel, dim3(2 * DD), dim3(256), 0, stream, w, vnz, vng, G);
    hipLaunchKernelGGL(out_kernel, dim3(16 * (DD / OB)), dim3(256), 0, stream, x, G, bias, out);
}